// Round 2
// 240.565 us; speedup vs baseline: 1.0722x; 1.0722x over previous
//
#include <hip/hip_runtime.h>

typedef __bf16 bf16;
typedef float f32x4 __attribute__((ext_vector_type(4)));
typedef bf16 bf16x8v __attribute__((ext_vector_type(8)));
typedef bf16 bf16x4v __attribute__((ext_vector_type(4)));

#define MFMA_BF16(a, b, c) __builtin_amdgcn_mfma_f32_16x16x32_bf16((a), (b), (c), 0, 0, 0)

// async global->LDS, 16B per lane (dest = wave-uniform base + lane*16)
__device__ __forceinline__ void async16(const bf16* g, bf16* l) {
  __builtin_amdgcn_global_load_lds(
      (const __attribute__((address_space(1))) void*)g,
      (__attribute__((address_space(3))) void*)l, 16, 0, 0);
}

// ---------------------------------------------------------------------------
// f32 -> bf16 convert, 8 elements/thread.
// ---------------------------------------------------------------------------
__global__ __launch_bounds__(256) void convert_kernel(
    const float* __restrict__ in, bf16* __restrict__ out, int n8) {
  int i = blockIdx.x * 256 + threadIdx.x;
  if (i >= n8) return;
  const float4* p = (const float4*)in + (size_t)i * 2;
  float4 a = p[0], b = p[1];
  bf16x8v o;
  o[0] = (bf16)a.x; o[1] = (bf16)a.y; o[2] = (bf16)a.z; o[3] = (bf16)a.w;
  o[4] = (bf16)b.x; o[5] = (bf16)b.y; o[6] = (bf16)b.z; o[7] = (bf16)b.w;
  ((bf16x8v*)out)[i] = o;
}

// ---------------------------------------------------------------------------
// Tiled transpose + f32->bf16: out[c][r] = (bf16)in[r][c].  R,C mult of 32.
// ---------------------------------------------------------------------------
__global__ __launch_bounds__(256) void transpose_conv_kernel(
    const float* __restrict__ in, bf16* __restrict__ out, int R, int Ccols) {
  __shared__ float tile[32][33];
  int c0 = blockIdx.x * 32, r0 = blockIdx.y * 32;
  int tx = threadIdx.x & 31;
  int ty = threadIdx.x >> 5;
#pragma unroll
  for (int i = 0; i < 4; ++i) {
    int r = ty + i * 8;
    tile[r][tx] = in[(size_t)(r0 + r) * Ccols + c0 + tx];
  }
  __syncthreads();
#pragma unroll
  for (int i = 0; i < 4; ++i) {
    int c = ty + i * 8;
    out[(size_t)(c0 + c) * R + r0 + tx] = (bf16)tile[tx][c];
  }
}

// ---------------------------------------------------------------------------
// Tiled bf16 transpose: out[z][c][r] = in[z][r][c].  R,C mult of 32.
// ---------------------------------------------------------------------------
__global__ __launch_bounds__(256) void transpose_bf16_kernel(
    const bf16* __restrict__ in, bf16* __restrict__ out, int R, int Ccols) {
  __shared__ bf16 tile[32][33];
  const bf16* inp = in + (size_t)blockIdx.z * R * Ccols;
  bf16* outp = out + (size_t)blockIdx.z * R * Ccols;
  int c0 = blockIdx.x * 32, r0 = blockIdx.y * 32;
  int tx = threadIdx.x & 31;
  int ty = threadIdx.x >> 5;
#pragma unroll
  for (int i = 0; i < 4; ++i) {
    int r = ty + i * 8;
    tile[r][tx] = inp[(size_t)(r0 + r) * Ccols + c0 + tx];
  }
  __syncthreads();
#pragma unroll
  for (int i = 0; i < 4; ++i) {
    int c = ty + i * 8;
    outp[(size_t)(c0 + c) * R + r0 + tx] = tile[tx][c];
  }
}

// ---------------------------------------------------------------------------
// GEMM: out[M][N] = A[M][768] * Bt[N][768]^T + bias[N]   (A,Bt bf16; bias f32)
// MODE 0: store FLOAT to outf.  MODE 1: scatter bf16 into q/k/v [b,h,t,d].
// 128x128 tile, BK=32, 4 waves, async global_load_lds staging (m97 pattern).
// ---------------------------------------------------------------------------
template <int MODE>
__global__ __launch_bounds__(256) void gemm_kernel(
    const bf16* __restrict__ A, const bf16* __restrict__ Bt,
    const float* __restrict__ bias, int N, float* __restrict__ outf,
    bf16* __restrict__ qo, bf16* __restrict__ ko, bf16* __restrict__ vo) {
  constexpr int Kdim = 768;
  __shared__ __align__(16) bf16 As[128][32];
  __shared__ __align__(16) bf16 Bs[128][32];
  const int tid = threadIdx.x;
  const int lane = tid & 63;
  const int wave = tid >> 6;
  const int wm = (wave >> 1) * 64, wn = (wave & 1) * 64;
  const int m0 = blockIdx.y * 128, n0 = blockIdx.x * 128;
  const int l15 = lane & 15, q4 = lane >> 4;

  f32x4 acc[4][4] = {};

  const int ca = wave * 2;
  const int ar = lane >> 2;
  const int ac = (lane & 3) * 8;
  bf16* asBase = &As[0][0];
  bf16* bsBase = &Bs[0][0];

  for (int k0 = 0; k0 < Kdim; k0 += 32) {
    const bf16* gA = A + (size_t)(m0 + ca * 16 + ar) * Kdim + k0 + ac;
    async16(gA, asBase + ca * 512);
    async16(gA + 16 * Kdim, asBase + (ca + 1) * 512);
    const bf16* gB = Bt + (size_t)(n0 + ca * 16 + ar) * Kdim + k0 + ac;
    async16(gB, bsBase + ca * 512);
    async16(gB + 16 * Kdim, bsBase + (ca + 1) * 512);
    __syncthreads();
    bf16x8v af[4], bfg[4];
#pragma unroll
    for (int i = 0; i < 4; ++i)
      af[i] = *(const bf16x8v*)&As[wm + i * 16 + l15][q4 * 8];
#pragma unroll
    for (int i = 0; i < 4; ++i)
      bfg[i] = *(const bf16x8v*)&Bs[wn + i * 16 + l15][q4 * 8];
#pragma unroll
    for (int mi = 0; mi < 4; ++mi)
#pragma unroll
      for (int ni = 0; ni < 4; ++ni)
        acc[mi][ni] = MFMA_BF16(af[mi], bfg[ni], acc[mi][ni]);
    __syncthreads();
  }

#pragma unroll
  for (int mi = 0; mi < 4; ++mi) {
#pragma unroll
    for (int ni = 0; ni < 4; ++ni) {
      int col = n0 + wn + ni * 16 + l15;
      float bv = bias[col];
#pragma unroll
      for (int r = 0; r < 4; ++r) {
        int row = m0 + wm + mi * 16 + q4 * 4 + r;
        float val = acc[mi][ni][r] + bv;
        if (MODE == 0) {
          outf[(size_t)row * N + col] = val;
        } else {
          int sel = col / 768;
          int cc = col - sel * 768;
          int h = cc >> 6, d = cc & 63;
          int b = row >> 12, t = row & 4095;
          bf16* dst = sel == 0 ? qo : (sel == 1 ? ko : vo);
          dst[((size_t)(b * 12 + h) * 4096 + t) * 64 + d] = (bf16)val;
        }
      }
    }
  }
}

// ---------------------------------------------------------------------------
// Flash attention (causal), fixed-max exp2 softmax, rowsum via MFMA, async
// double-buffered swizzled staging.
//
// Mirror-pair block: block handles q-tiles {63-p, p}; tile p's key range is
// a subset of tile 63-p's, so ONE staged K/V stream of 64-p tiles serves
// both.  BALANCED STRIPS: every wave owns one 16-row strip of EACH tile
// (strip0 = big tile row (63-p)*64+wave*16, strip1 = p*64+wave*16), so
// per-iter work is identical across all 4 waves — no barrier idle.
//
// QK^T is computed SWAPPED — mfma(K,Q) — so a lane (g=q4,l15) holds, for
// q-row l15, keys {ni*16+g*4+r}: four contiguous 4-key runs.  P therefore
// reaches LDS with FOUR ds_write_b64 per strip (vs 32 scalar u16 writes),
// at unswizzled col ni*16+g*4 of row l15; the swizzled ds_read_b128 PV
// A-frag read is byte-identical to the proven baseline path.
// 48 KB LDS -> 3 blocks/CU = 12 waves/CU.
// ---------------------------------------------------------------------------
__global__ __launch_bounds__(256, 3) void attn_kernel(
    const bf16* __restrict__ q, const bf16* __restrict__ k,
    const bf16* __restrict__ vt, bf16* __restrict__ y) {
  __shared__ __align__(16) bf16 Kb[2][64][64];  // [key][d], swizzled
  __shared__ __align__(16) bf16 Vb[2][64][64];  // [d][key], swizzled
  __shared__ __align__(16) bf16 Ps[4][32][64];  // per-wave P, swizzled
  const int tid = threadIdx.x;
  const int lane = tid & 63, wave = tid >> 6;  // wave 0..3
  const int l15 = lane & 15, q4 = lane >> 4;
  const int swz = l15 & 7;
  const int id = blockIdx.x;
  const int bh = id % 24;
  const int p = id / 24;                        // 0..31
  const int rs0 = (63 - p) * 64 + wave * 16;    // big-tile strip (always live)
  const int rs1 = p * 64 + wave * 16;           // small-tile strip (kt<=p)
  const int hb = bh % 12, bb = bh / 12;

  // staging geometry: one async16 wave-call covers 8 rows x 8 chunks (1 KB)
  const int gr = lane >> 3;        // row within 8-row group
  const int sj = (lane & 7) ^ gr;  // global source chunk (XOR swizzle)
  const bf16* kgbase = k + (size_t)bh * 4096 * 64;
  const bf16* vgbase = vt + (size_t)bh * 64 * 4096;

  bf16x8v ones;
#pragma unroll
  for (int j = 0; j < 8; ++j) ones[j] = (bf16)1.0f;

  // Q fragments, pre-scaled by log2(e)/sqrt(64) (exp2-domain scores)
  bf16x8v qf[2][2];
#pragma unroll
  for (int st = 0; st < 2; ++st) {
    const int rs = st ? rs1 : rs0;
    const bf16* qrow = q + ((size_t)bh * 4096 + rs + l15) * 64 + q4 * 8;
#pragma unroll
    for (int ks = 0; ks < 2; ++ks) {
      bf16x8v t8 = *(const bf16x8v*)(qrow + ks * 32);
#pragma unroll
      for (int j = 0; j < 8; ++j) t8[j] = (bf16)((float)t8[j] * 0.18033688f);
      qf[st][ks] = t8;
    }
  }

  f32x4 o0[4] = {}, o1[4] = {};
  f32x4 ol0 = {}, ol1 = {};

  auto stage = [&](int kt, int buf) {
    const int t0k = kt * 64;
#pragma unroll
    for (int g = 0; g < 2; ++g) {
      const int grp = wave * 2 + g;  // 8-row group 0..7
      async16(kgbase + (size_t)(t0k + grp * 8 + gr) * 64 + sj * 8,
              &Kb[buf][grp * 8][0]);
      async16(vgbase + (size_t)(grp * 8 + gr) * 4096 + t0k + sj * 8,
              &Vb[buf][grp * 8][0]);
    }
  };

  // p = exp2(s - 28.854); full (no mask) variant
  auto sm_full = [&](f32x4 (&s)[4]) {
#pragma unroll
    for (int ni = 0; ni < 4; ++ni)
#pragma unroll
      for (int r = 0; r < 4; ++r)
        s[ni][r] = __builtin_amdgcn_exp2f(s[ni][r] - 28.8539008f);
  };
  // masked variant: local key (ni*16+q4*4+r) valid iff <= lim
  auto sm_mask = [&](f32x4 (&s)[4], int lim) {
#pragma unroll
    for (int ni = 0; ni < 4; ++ni)
#pragma unroll
      for (int r = 0; r < 4; ++r)
        s[ni][r] = (ni * 16 + q4 * 4 + r <= lim)
                       ? __builtin_amdgcn_exp2f(s[ni][r] - 28.8539008f)
                       : 0.0f;
  };
  // P row write: lane (q4,l15) owns keys ni*16 + q4*4 + {0..3} of q-row l15.
  // Unswizzled elem col = ni*16 + q4*4; block jb = ni*2 + (q4>>1), offset
  // (q4&1)*4.  Swizzle XORs block with row&7 (matches baseline read path).
  auto pwrite = [&](const f32x4 (&s)[4], int row) {
#pragma unroll
    for (int ni = 0; ni < 4; ++ni) {
      bf16x4v pv4;
#pragma unroll
      for (int e = 0; e < 4; ++e) pv4[e] = (bf16)s[ni][e];
      const int jb = ni * 2 + (q4 >> 1);
      *(bf16x4v*)&Ps[wave][row][((jb ^ (row & 7)) * 8) + (q4 & 1) * 4] = pv4;
    }
  };

  const int ktmax = 64 - p;  // tiles needed by the big tile
  stage(0, 0);

  for (int kt = 0; kt < ktmax; ++kt) {
    const int buf = kt & 1;
    __syncthreads();  // drains vmcnt: tile kt resident; buf^1 free
    if (kt + 1 < ktmax) stage(kt + 1, buf ^ 1);
    const int t0 = kt * 64;
    const bool act1 = (t0 <= rs1 + 15);  // block-uniform: kt <= p

    // S^T = K Q^T (exp2 domain); strips share kf loads.
    // Lane (q4,l15): s[ni][r] = S[q_row = rs + l15][key = t0+ni*16+q4*4+r]
    f32x4 s0[4] = {}, s1[4] = {};
    __builtin_amdgcn_s_setprio(1);
    if (act1) {
#pragma unroll
      for (int ni = 0; ni < 4; ++ni) {
#pragma unroll
        for (int ks = 0; ks < 2; ++ks) {
          bf16x8v kf = *(const bf16x8v*)&Kb[buf][ni * 16 + l15]
                                           [((ks * 4 + q4) ^ swz) * 8];
          s0[ni] = MFMA_BF16(kf, qf[0][ks], s0[ni]);
          s1[ni] = MFMA_BF16(kf, qf[1][ks], s1[ni]);
        }
      }
    } else {
#pragma unroll
      for (int ni = 0; ni < 4; ++ni) {
#pragma unroll
        for (int ks = 0; ks < 2; ++ks) {
          bf16x8v kf = *(const bf16x8v*)&Kb[buf][ni * 16 + l15]
                                           [((ks * 4 + q4) ^ swz) * 8];
          s0[ni] = MFMA_BF16(kf, qf[0][ks], s0[ni]);
        }
      }
    }
    __builtin_amdgcn_s_setprio(0);

    // softmax + P writes (strip0 rows 0..15, strip1 rows 16..31 of Ps)
    if (t0 + 63 <= rs0) sm_full(s0); else sm_mask(s0, rs0 + l15 - t0);
    pwrite(s0, l15);
    if (act1) {
      if (t0 + 63 <= rs1) sm_full(s1); else sm_mask(s1, rs1 + l15 - t0);
      pwrite(s1, 16 + l15);
    }

    // PV A-frags: proven swizzled b128 read path (row = q_row = l15)
    bf16x8v pf0[2], pf1[2];
#pragma unroll
    for (int ks = 0; ks < 2; ++ks)
      pf0[ks] = *(const bf16x8v*)&Ps[wave][l15][((ks * 4 + q4) ^ swz) * 8];
    if (act1) {
#pragma unroll
      for (int ks = 0; ks < 2; ++ks)
        pf1[ks] =
            *(const bf16x8v*)&Ps[wave][16 + l15][((ks * 4 + q4) ^ swz) * 8];
      // O += P V ; rowsum l += P * ones   (shared vf loads)
      __builtin_amdgcn_s_setprio(1);
#pragma unroll
      for (int d4 = 0; d4 < 4; ++d4) {
#pragma unroll
        for (int ks = 0; ks < 2; ++ks) {
          bf16x8v vf = *(const bf16x8v*)&Vb[buf][d4 * 16 + l15]
                                           [((ks * 4 + q4) ^ swz) * 8];
          o0[d4] = MFMA_BF16(pf0[ks], vf, o0[d4]);
          o1[d4] = MFMA_BF16(pf1[ks], vf, o1[d4]);
        }
      }
#pragma unroll
      for (int ks = 0; ks < 2; ++ks) {
        ol0 = MFMA_BF16(pf0[ks], ones, ol0);
        ol1 = MFMA_BF16(pf1[ks], ones, ol1);
      }
      __builtin_amdgcn_s_setprio(0);
    } else {
      __builtin_amdgcn_s_setprio(1);
#pragma unroll
      for (int d4 = 0; d4 < 4; ++d4) {
#pragma unroll
        for (int ks = 0; ks < 2; ++ks) {
          bf16x8v vf = *(const bf16x8v*)&Vb[buf][d4 * 16 + l15]
                                           [((ks * 4 + q4) ^ swz) * 8];
          o0[d4] = MFMA_BF16(pf0[ks], vf, o0[d4]);
        }
      }
#pragma unroll
      for (int ks = 0; ks < 2; ++ks) ol0 = MFMA_BF16(pf0[ks], ones, ol0);
      __builtin_amdgcn_s_setprio(0);
    }
  }

  // epilogue: y[b][t][h*64+d] = O / l  (fixed-max scale cancels)
  // PV output D-layout: q_row = rs + q4*4 + r, d = d4*16 + l15.
#pragma unroll
  for (int d4 = 0; d4 < 4; ++d4)
#pragma unroll
    for (int r = 0; r < 4; ++r) {
      int row0 = rs0 + q4 * 4 + r;
      y[((size_t)(bb * 4096 + row0)) * 768 + hb * 64 + d4 * 16 + l15] =
          (bf16)(o0[d4][r] / ol0[r]);
      int row1 = rs1 + q4 * 4 + r;
      y[((size_t)(bb * 4096 + row1)) * 768 + hb * 64 + d4 * 16 + l15] =
          (bf16)(o1[d4][r] / ol1[r]);
    }
}

// ---------------------------------------------------------------------------
extern "C" void kernel_launch(void* const* d_in, const int* in_sizes, int n_in,
                              void* d_out, int out_size, void* d_ws,
                              size_t ws_size, hipStream_t stream) {
  const float* x = (const float*)d_in[0];       // (2,4096,768) f32
  const float* w_attn = (const float*)d_in[1];  // (768,2304) f32
  const float* b_attn = (const float*)d_in[2];  // (2304) f32
  const float* w_proj = (const float*)d_in[3];  // (768,768) f32
  const float* b_proj = (const float*)d_in[4];  // (768) f32
  float* out = (float*)d_out;                   // (8192*768) f32

  char* ws = (char*)d_ws;
  size_t off = 0;
  auto carve = [&](size_t elems) {
    char* p = ws + off;
    off += ((elems * sizeof(bf16) + 255) & ~(size_t)255);
    return (bf16*)p;
  };
  bf16* xb = carve((size_t)8192 * 768);      // x bf16; reused as vtb
  bf16* wt_attn = carve((size_t)2304 * 768);
  bf16* wt_proj = carve((size_t)768 * 768);
  bf16* qb = carve((size_t)24 * 4096 * 64);
  bf16* kb = carve((size_t)24 * 4096 * 64);
  bf16* vb = carve((size_t)24 * 4096 * 64);  // reused as yb
  bf16* vtb = xb;  // xb dead after QKV gemm
  bf16* yb = vb;   // vb dead after V transpose

  convert_kernel<<<(8192 * 768 / 8 + 255) / 256, 256, 0, stream>>>(
      x, xb, 8192 * 768 / 8);
  transpose_conv_kernel<<<dim3(2304 / 32, 768 / 32), 256, 0, stream>>>(
      w_attn, wt_attn, 768, 2304);
  transpose_conv_kernel<<<dim3(768 / 32, 768 / 32), 256, 0, stream>>>(
      w_proj, wt_proj, 768, 768);
  gemm_kernel<1><<<dim3(2304 / 128, 8192 / 128), 256, 0, stream>>>(
      xb, wt_attn, b_attn, 2304, nullptr, qb, kb, vb);
  transpose_bf16_kernel<<<dim3(64 / 32, 4096 / 32, 24), 256, 0, stream>>>(
      vb, vtb, 4096, 64);
  attn_kernel<<<dim3(768), 256, 0, stream>>>(qb, kb, vtb, yb);
  gemm_kernel<0><<<dim3(768 / 128, 8192 / 128), 256, 0, stream>>>(
      yb, wt_proj, b_proj, 768, out, nullptr, nullptr, nullptr);
}